// Round 2
// baseline (87.350 us; speedup 1.0000x reference)
//
#include <hip/hip_runtime.h>

constexpr int B   = 1024;
constexpr int N   = 4096;
constexpr int BLK = 256;
constexpr int VPT = 4;                    // consecutive n per thread per group
constexpr int GROUPS = N / (BLK * VPT);   // = 4
constexpr float C01 = 0.4082482904638630f;  // sqrt(0.5)/sqrt(3)
constexpr float C11 = 0.2886751345948129f;  // sqrt(0.5)/sqrt(6)

// One block per batch row: reduce tp_out over N, then run the 3->128->3 MLP.
__global__ __launch_bounds__(BLK) void fused_kernel(
    const float* __restrict__ feats,      // (B, N, 8)
    const float* __restrict__ edge_attr,  // (B, N, 3)
    const float* __restrict__ w_path0,    // (5,)
    const float* __restrict__ w_path1,    // (1,)
    const float* __restrict__ W1,         // (3, 128) row-major
    const float* __restrict__ b1,         // (128,)
    const float* __restrict__ W2,         // (128, 3) row-major
    const float* __restrict__ b2,         // (3,)
    float* __restrict__ out)              // (B, 3)
{
    const int b   = blockIdx.x;
    const int tid = threadIdx.x;

    const float w0 = w_path0[0], w1 = w_path0[1], w2 = w_path0[2],
                w3 = w_path0[3], w4 = w_path0[4];
    const float c11w = C11 * w_path1[0];

    float acc0 = 0.0f, acc1 = 0.0f, acc2 = 0.0f;

    for (int grp = 0; grp < GROUPS; ++grp) {
        const int n0 = grp * (BLK * VPT) + tid * VPT;
        const long idx = (long)b * N + n0;

        // feats: 128 contiguous bytes per lane -> 8 float4
        const float4* fp = reinterpret_cast<const float4*>(feats + idx * 8);
        float4 F[8];
        #pragma unroll
        for (int i = 0; i < 8; ++i) F[i] = fp[i];
        const float* f = reinterpret_cast<const float*>(F);

        // edge_attr: 48 contiguous bytes per lane, 16B-aligned -> 3 float4
        const float4* ep = reinterpret_cast<const float4*>(edge_attr + idx * 3);
        float4 E[3];
        #pragma unroll
        for (int i = 0; i < 3; ++i) E[i] = ep[i];
        const float* e = reinterpret_cast<const float*>(E);

        #pragma unroll
        for (int k = 0; k < VPT; ++k) {
            const float* fk = f + k * 8;
            const float* ek = e + k * 3;
            float s = fk[0] * w0 + fk[1] * w1 + fk[2] * w2 + fk[3] * w3 + fk[4] * w4;
            float c01s = C01 * s;
            float v0 = fk[5], v1 = fk[6], v2 = fk[7];
            float e0 = ek[0], e1 = ek[1], e2 = ek[2];
            acc0 += c01s * e0 + c11w * (v1 * e2 - v2 * e1);
            acc1 += c01s * e1 + c11w * (v2 * e0 - v0 * e2);
            acc2 += c01s * e2 + c11w * (v0 * e1 - v1 * e0);
        }
    }

    // 64-lane wave reduction
    #pragma unroll
    for (int off = 32; off > 0; off >>= 1) {
        acc0 += __shfl_down(acc0, off);
        acc1 += __shfl_down(acc1, off);
        acc2 += __shfl_down(acc2, off);
    }

    __shared__ float wsum[4][3];
    const int wave = tid >> 6;
    const int lane = tid & 63;
    if (lane == 0) {
        wsum[wave][0] = acc0;
        wsum[wave][1] = acc1;
        wsum[wave][2] = acc2;
    }
    __syncthreads();

    __shared__ float g[3];
    if (tid < 3) {
        g[tid] = (wsum[0][tid] + wsum[1][tid] + wsum[2][tid] + wsum[3][tid])
               * (1.0f / (float)N);
    }
    __syncthreads();

    // MLP: 3 -> 128 (relu) -> 3. Threads 0..127 each own one hidden unit.
    float p0 = 0.0f, p1 = 0.0f, p2 = 0.0f;
    if (tid < 128) {
        float h = b1[tid] + g[0] * W1[tid] + g[1] * W1[128 + tid] + g[2] * W1[256 + tid];
        h = fmaxf(h, 0.0f);
        p0 = h * W2[tid * 3 + 0];
        p1 = h * W2[tid * 3 + 1];
        p2 = h * W2[tid * 3 + 2];
    }
    #pragma unroll
    for (int off = 32; off > 0; off >>= 1) {
        p0 += __shfl_down(p0, off);
        p1 += __shfl_down(p1, off);
        p2 += __shfl_down(p2, off);
    }
    __shared__ float pr[4][3];
    if (lane == 0) {
        pr[wave][0] = p0;
        pr[wave][1] = p1;
        pr[wave][2] = p2;
    }
    __syncthreads();
    if (tid < 3) {
        out[(long)b * 3 + tid] = pr[0][tid] + pr[1][tid] + b2[tid];
    }
}

extern "C" void kernel_launch(void* const* d_in, const int* in_sizes, int n_in,
                              void* d_out, int out_size, void* d_ws, size_t ws_size,
                              hipStream_t stream) {
    const float* feats     = (const float*)d_in[0];
    const float* edge_attr = (const float*)d_in[1];
    const float* w_path0   = (const float*)d_in[2];
    const float* w_path1   = (const float*)d_in[3];
    const float* W1        = (const float*)d_in[4];
    const float* b1        = (const float*)d_in[5];
    const float* W2        = (const float*)d_in[6];
    const float* b2        = (const float*)d_in[7];
    float* out = (float*)d_out;

    fused_kernel<<<B, BLK, 0, stream>>>(feats, edge_attr, w_path0, w_path1,
                                        W1, b1, W2, b2, out);
}

// Round 3
// 34.828 us; speedup vs baseline: 2.5080x; 2.5080x over previous
//
#include <hip/hip_runtime.h>

constexpr int B   = 1024;
constexpr int N   = 4096;
constexpr int BLK = 256;                 // stage-1 block = 4 waves
constexpr int WAVES_PER_BATCH = 64;      // 16 blocks * 4 waves
constexpr float C01 = 0.4082482904638630f;  // sqrt(0.5)/sqrt(3)
constexpr float C11 = 0.2886751345948129f;  // sqrt(0.5)/sqrt(6)

typedef float f32x4 __attribute__((ext_vector_type(4)));

// Stage 1: grid = B*16 blocks x 256 threads, one n per thread.
// Pure shuffle reduction; each wave writes its own 3-float partial.
__global__ __launch_bounds__(BLK) void tp_reduce_kernel(
    const float* __restrict__ feats,      // (B, N, 8)
    const float* __restrict__ edge_attr,  // (B, N, 3)
    const float* __restrict__ w_path0,    // (5,)
    const float* __restrict__ w_path1,    // (1,)
    float* __restrict__ part)             // (B*64, 3) per-wave partials
{
    const int blk = blockIdx.x;
    const int b   = blk >> 4;
    const int n   = ((blk & 15) << 8) + threadIdx.x;
    const long idx = (long)b * N + n;

    const f32x4* fp = reinterpret_cast<const f32x4*>(feats + idx * 8);
    f32x4 f0 = __builtin_nontemporal_load(fp);
    f32x4 f1 = __builtin_nontemporal_load(fp + 1);

    const float* ep = edge_attr + idx * 3;
    float e0 = __builtin_nontemporal_load(ep);
    float e1 = __builtin_nontemporal_load(ep + 1);
    float e2 = __builtin_nontemporal_load(ep + 2);

    float s = f0.x * w_path0[0] + f0.y * w_path0[1] + f0.z * w_path0[2]
            + f0.w * w_path0[3] + f1.x * w_path0[4];
    float c01s = C01 * s;
    float c11w = C11 * w_path1[0];
    float v0 = f1.y, v1 = f1.z, v2 = f1.w;

    float t0 = c01s * e0 + c11w * (v1 * e2 - v2 * e1);
    float t1 = c01s * e1 + c11w * (v2 * e0 - v0 * e2);
    float t2 = c01s * e2 + c11w * (v0 * e1 - v1 * e0);

    #pragma unroll
    for (int off = 32; off > 0; off >>= 1) {
        t0 += __shfl_down(t0, off);
        t1 += __shfl_down(t1, off);
        t2 += __shfl_down(t2, off);
    }

    if ((threadIdx.x & 63) == 0) {
        // wave index within batch: blk_in_batch*4 + wave_in_block
        const int w = ((blk & 15) << 2) + (threadIdx.x >> 6);
        float* p = part + ((long)b * WAVES_PER_BATCH + w) * 3;
        p[0] = t0;
        p[1] = t1;
        p[2] = t2;
    }
}

// Stage 2: one wave per batch. Sum 64 partials, then MLP 3->128(relu)->3.
__global__ __launch_bounds__(64) void mlp_kernel(
    const float* __restrict__ part,  // (B*64, 3)
    const float* __restrict__ W1,    // (3, 128)
    const float* __restrict__ b1,    // (128,)
    const float* __restrict__ W2,    // (128, 3)
    const float* __restrict__ b2,    // (3,)
    float* __restrict__ out)         // (B, 3)
{
    const int b = blockIdx.x;
    const int l = threadIdx.x;  // 0..63

    const float* p = part + ((long)b * WAVES_PER_BATCH + l) * 3;
    float a0 = p[0], a1 = p[1], a2 = p[2];

    #pragma unroll
    for (int off = 32; off > 0; off >>= 1) {
        a0 += __shfl_down(a0, off);
        a1 += __shfl_down(a1, off);
        a2 += __shfl_down(a2, off);
    }
    const float g0 = __shfl(a0, 0) * (1.0f / (float)N);
    const float g1 = __shfl(a1, 0) * (1.0f / (float)N);
    const float g2 = __shfl(a2, 0) * (1.0f / (float)N);

    // hidden units j = l and j = l + 64
    float p0 = 0.0f, p1 = 0.0f, p2 = 0.0f;
    #pragma unroll
    for (int half = 0; half < 2; ++half) {
        const int j = l + half * 64;
        float h = b1[j] + g0 * W1[j] + g1 * W1[128 + j] + g2 * W1[256 + j];
        h = fmaxf(h, 0.0f);
        p0 += h * W2[j * 3 + 0];
        p1 += h * W2[j * 3 + 1];
        p2 += h * W2[j * 3 + 2];
    }
    #pragma unroll
    for (int off = 32; off > 0; off >>= 1) {
        p0 += __shfl_down(p0, off);
        p1 += __shfl_down(p1, off);
        p2 += __shfl_down(p2, off);
    }
    if (l == 0) {
        float* o = out + (long)b * 3;
        o[0] = p0 + b2[0];
        o[1] = p1 + b2[1];
        o[2] = p2 + b2[2];
    }
}

extern "C" void kernel_launch(void* const* d_in, const int* in_sizes, int n_in,
                              void* d_out, int out_size, void* d_ws, size_t ws_size,
                              hipStream_t stream) {
    const float* feats     = (const float*)d_in[0];
    const float* edge_attr = (const float*)d_in[1];
    const float* w_path0   = (const float*)d_in[2];
    const float* w_path1   = (const float*)d_in[3];
    const float* W1        = (const float*)d_in[4];
    const float* b1        = (const float*)d_in[5];
    const float* W2        = (const float*)d_in[6];
    const float* b2        = (const float*)d_in[7];
    float* out = (float*)d_out;

    float* part = (float*)d_ws;  // B*64*3 floats = 768 KiB

    tp_reduce_kernel<<<B * 16, BLK, 0, stream>>>(feats, edge_attr, w_path0,
                                                 w_path1, part);
    mlp_kernel<<<B, 64, 0, stream>>>(part, W1, b1, W2, b2, out);
}